// Round 5
// baseline (162.548 us; speedup 1.0000x reference)
//
#include <hip/hip_runtime.h>

// Dims fixed by setup_inputs(): B=4, C=64, H=W=64 -> T=4096, HEADS=8, dh=8, k=T/4=1024
#define T_DIM 4096
#define KD    1024
#define SCALE 0.35355339059327373f   // 8^-0.5
// K-scale with log2(e) folded in so attn uses native v_exp_f32 (2^x) directly
#define SCALE2 (0.35355339059327373f * 1.4426950408889634f)
#define VT_PITCH 1032

extern "C" __device__ float __ocml_native_exp2_f32(float);   // single v_exp_f32

typedef __attribute__((ext_vector_type(8))) short bf16x8;
typedef __attribute__((ext_vector_type(4))) short bf16x4;
typedef __attribute__((ext_vector_type(4))) float f32x4;

__device__ inline unsigned short f2bf(float f) {   // RNE fp32 -> bf16
  unsigned u = __float_as_uint(f);
  unsigned r = u + 0x7fffu + ((u >> 16) & 1u);
  return (unsigned short)(r >> 16);
}

__device__ inline unsigned cvt_pk_bf16(float a, float b) {  // a->lo, b->hi (RNE)
  unsigned ua = __float_as_uint(a); ua += 0x7fffu + ((ua >> 16) & 1u);
  unsigned ub = __float_as_uint(b); ub += 0x7fffu + ((ub >> 16) & 1u);
  return (ua >> 16) | (ub & 0xffff0000u);
}

__device__ inline unsigned pk_trunc(float a, float b) {     // truncating pack
  return (__float_as_uint(a) >> 16) | (__float_as_uint(b) & 0xffff0000u);
}

__device__ inline bf16x4 mk4(unsigned lo, unsigned hi) {
  union { unsigned u[2]; bf16x4 v; } x; x.u[0] = lo; x.u[1] = hi; return x.v;
}

__device__ inline bf16x8 mk8(unsigned a, unsigned b, unsigned c, unsigned d) {
  union { unsigned u[4]; bf16x8 v; } x;
  x.u[0] = a; x.u[1] = b; x.u[2] = c; x.u[3] = d; return x.v;
}

// 16x16x16 bf16 MFMA semantics via the verified 16x16x32 builtin (j=4..7 zero).
__device__ inline f32x4 mfma16(bf16x4 a, bf16x4 b, f32x4 c) {
  bf16x8 a8 = {}, b8 = {};
  a8[0] = a[0]; a8[1] = a[1]; a8[2] = a[2]; a8[3] = a[3];
  b8[0] = b[0]; b8[1] = b[1]; b8[2] = b[2]; b8[3] = b[3];
  return __builtin_amdgcn_mfma_f32_16x16x32_bf16(a8, b8, c, 0, 0, 0);
}

// ---------------------------------------------------------------------------
// K1 "front": 256 blocks, xe only — partial[s*4+b][c][k] = (x[b]@E) 512-row
//             t-slice (s=0..7, 16 tb-iters). Q is now computed inside k_attn.
//   ALSO: zeroes d_out (4 float4/thread) for k_attn's atomicAdd.
// ---------------------------------------------------------------------------
__global__ __launch_bounds__(256) void k_front(const float* __restrict__ x,
                                               const float* __restrict__ E,
                                               float* __restrict__ partial,
                                               float* __restrict__ out) {
  const int bid = blockIdx.x;
  const int tid = threadIdx.x;

  {  // zero d_out: 256 blocks * 256 thr * 4 float4 = 4 MB, coalesced
    float4* o4 = (float4*)out;
#pragma unroll
    for (int u = 0; u < 4; ++u)
      o4[(size_t)bid * 1024 + u * 256 + tid] = make_float4(0.f, 0.f, 0.f, 0.f);
  }

  const int kb = bid & 7;
  const int b  = (bid >> 3) & 3;
  const int s  = bid >> 5;                   // 0..7 (512 t-rows each)
  const int k0 = kb * 128;
  const int lane = tid & 63;
  const int w = tid >> 6;
  const int li = lane & 15, lg = lane >> 4;

  f32x4 acc[4][2] = {};
#pragma unroll 2
  for (int tb = 0; tb < 16; ++tb) {
    const int tbase = s * 512 + tb * 32 + lg * 8;
    bf16x8 bq[2];
#pragma unroll
    for (int nt = 0; nt < 2; ++nt) {
      const int kcol = k0 + w * 32 + nt * 16 + li;
      float bv[8];
#pragma unroll
      for (int j = 0; j < 8; ++j)
        bv[j] = E[(size_t)(tbase + j) * KD + kcol];
      bq[nt] = mk8(cvt_pk_bf16(bv[0], bv[1]), cvt_pk_bf16(bv[2], bv[3]),
                   cvt_pk_bf16(bv[4], bv[5]), cvt_pk_bf16(bv[6], bv[7]));
    }
#pragma unroll
    for (int mt = 0; mt < 4; ++mt) {
      const float* ap = x + ((size_t)b * 64 + mt * 16 + li) * T_DIM + tbase;
      float4 a0 = *(const float4*)(ap);
      float4 a1 = *(const float4*)(ap + 4);
      bf16x8 af8 = mk8(cvt_pk_bf16(a0.x, a0.y), cvt_pk_bf16(a0.z, a0.w),
                       cvt_pk_bf16(a1.x, a1.y), cvt_pk_bf16(a1.z, a1.w));
      acc[mt][0] = __builtin_amdgcn_mfma_f32_16x16x32_bf16(af8, bq[0], acc[mt][0], 0, 0, 0);
      acc[mt][1] = __builtin_amdgcn_mfma_f32_16x16x32_bf16(af8, bq[1], acc[mt][1], 0, 0, 0);
    }
  }
  float* pb = partial + ((size_t)s * 4 + b) * (64 * KD);
#pragma unroll
  for (int mt = 0; mt < 4; ++mt)
#pragma unroll
    for (int nt = 0; nt < 2; ++nt) {
      const int row = mt * 16 + lg * 4;
      const int col = k0 + w * 32 + nt * 16 + li;
#pragma unroll
      for (int reg = 0; reg < 4; ++reg)
        pb[(size_t)(row + reg) * KD + col] = acc[mt][nt][reg];
    }
}

// ---------------------------------------------------------------------------
// K2 "xkv": s-reduce (8 slices, fp32 into LDS) + K/V projection, fused.
//   Grid (kb 16, h 8, b 4). Proven in R4.
// ---------------------------------------------------------------------------
__global__ __launch_bounds__(256) void k_xkv(const float* __restrict__ partial,
                                             const float* __restrict__ Wqkv,
                                             uint2* __restrict__ Kg,
                                             unsigned short* __restrict__ Vg) {
  __shared__ float XPs[64 * 64];               // [c][k-local] fp32, 16 KB
  const int kb = blockIdx.x;                   // 0..15 -> k0 = kb*64
  const int h  = blockIdx.y;                   // 0..7
  const int b  = blockIdx.z;                   // 0..3
  const int tid = threadIdx.x;

  {
    const int kk = tid & 63;
    const int cg = tid >> 6;                   // 0..3
#pragma unroll 4
    for (int u = 0; u < 16; ++u) {
      const int c = cg * 16 + u;
      const size_t src = (size_t)c * KD + kb * 64 + kk;
      float a = 0.f;
#pragma unroll
      for (int s = 0; s < 8; ++s)
        a += partial[((size_t)s * 4 + b) * (64 * KD) + src];
      XPs[c * 64 + kk] = a;
    }
  }
  __syncthreads();

  const int klocal = tid & 63;
  const int sel    = (tid >> 6) & 1;           // wave-uniform: 0=K, 1=V
  const int dg     = tid >> 7;                 // wave-uniform: d-group 0/1
  const int k      = kb * 64 + klocal;

  float acc[4];
#pragma unroll
  for (int d = 0; d < 4; ++d) acc[d] = 0.f;
#pragma unroll 8
  for (int c = 0; c < 64; ++c) {
    float xv = XPs[c * 64 + klocal];                 // LDS, conflict-free
    const float* wr = Wqkv + c * 192 + (sel + 1) * 8 + h;            // s_load
#pragma unroll
    for (int d = 0; d < 4; ++d) acc[d] += xv * wr[(dg * 4 + d) * 24];
  }

  const int bh = b * 8 + h;
  if (sel == 0) {
    uint2* kg = Kg + (size_t)bh * 2048;
    kg[dg * 1024 + k] = make_uint2(cvt_pk_bf16(acc[0] * SCALE2, acc[1] * SCALE2),
                                   cvt_pk_bf16(acc[2] * SCALE2, acc[3] * SCALE2));
  } else {
#pragma unroll
    for (int d = 0; d < 4; ++d)
      Vg[(size_t)(bh * 8 + dg * 4 + d) * KD + k] = f2bf(acc[d]);
  }
}

// ---------------------------------------------------------------------------
// K3: MFMA flash attention + fused out-projection. Grid (bh 32, iy 32) =
//     1024 blocks -> 4 blocks/CU (LDS 39 KB), 16 waves/CU: fixes R4's
//     2-blocks/CU latency stall (Occ 16%, VALUBusy 42%).
//     NEW: computes its own Q fragment in-register from x + LDS-staged Wq
//     h-slice (same fp32 accumulation order as the old k_front q-part), so
//     the Q workspace and front's 512 q-blocks are gone.
//     jt-loop and epilogue are R1's proven bodies (exp = native v_exp_f32,
//     log2e folded into K's scale).
// ---------------------------------------------------------------------------
__global__ __launch_bounds__(256) void k_attn(const float* __restrict__ x,
                                              const float* __restrict__ Wqkv,
                                              const uint2* __restrict__ Kg,
                                              const unsigned short* __restrict__ Vg,
                                              const float* __restrict__ W0,
                                              float* __restrict__ out) {
  __shared__ __attribute__((aligned(16))) unsigned short Kt[2 * 1024 * 4];  // 16 KB
  __shared__ unsigned short Vt[9 * VT_PITCH];   // [d][j] bf16, row 8 = ones
  __shared__ float W0s[512];                    // W0[h*8+d][c], d<8, c<64
  __shared__ float Wqh[512];                    // Wq[c][d] h-slice, 2 KB
  const int bh = blockIdx.x;
  const int tid = threadIdx.x;
  const int b = bh >> 3, h = bh & 7;

  const uint2* kg = Kg + (size_t)bh * 2048;
  uint2* kt2 = (uint2*)Kt;
#pragma unroll
  for (int it = 0; it < 8; ++it)
    kt2[it * 256 + tid] = kg[it * 256 + tid];
  const unsigned* vg = (const unsigned*)(Vg + (size_t)bh * 8192);
#pragma unroll
  for (int dd = 0; dd < 8; ++dd) {
#pragma unroll
    for (int it = 0; it < 2; ++it) {
      const int j2 = it * 256 + tid;
      *(unsigned*)(Vt + dd * VT_PITCH + j2 * 2) = vg[dd * 512 + j2];
    }
  }
#pragma unroll
  for (int it = 0; it < 2; ++it)
    *(unsigned*)(Vt + 8 * VT_PITCH + (it * 256 + tid) * 2) = 0x3F803F80u;  // ones
  W0s[tid]       = W0[h * 512 + tid];          // rows h*8..h*8+7, coalesced
  W0s[tid + 256] = W0[h * 512 + tid + 256];
#pragma unroll
  for (int e = tid; e < 512; e += 256) {       // Wqh[c*8+d] = Wqkv[c,d*24+h]
    const int c = e >> 3, d = e & 7;
    Wqh[e] = Wqkv[c * 192 + d * 24 + h];
  }
  __syncthreads();

  const int lane = tid & 63, w = tid >> 6;
  const int li = lane & 15, lg = lane >> 4;
  const int i0w = blockIdx.y * 128 + w * 32;

  // ---- in-register Q projection: Q[d=lg*4+j][t=i0w+it2*16+li] ----
  bf16x4 qf[2] = {bf16x4{}, bf16x4{}};
  if (lane < 32) {
    float qa0[4] = {0.f, 0.f, 0.f, 0.f}, qa1[4] = {0.f, 0.f, 0.f, 0.f};
    const float* xb = x + (size_t)b * 64 * T_DIM + i0w + li;
#pragma unroll 4
    for (int c = 0; c < 64; ++c) {
      const float4 wq = *(const float4*)(&Wqh[c * 8 + lg * 4]);  // LDS bcast
      const float xv0 = xb[(size_t)c * T_DIM];        // 64-B segment / wave
      const float xv1 = xb[(size_t)c * T_DIM + 16];
      qa0[0] += xv0 * wq.x; qa0[1] += xv0 * wq.y;
      qa0[2] += xv0 * wq.z; qa0[3] += xv0 * wq.w;
      qa1[0] += xv1 * wq.x; qa1[1] += xv1 * wq.y;
      qa1[2] += xv1 * wq.z; qa1[3] += xv1 * wq.w;
    }
    qf[0] = mk4(cvt_pk_bf16(qa0[0], qa0[1]), cvt_pk_bf16(qa0[2], qa0[3]));
    qf[1] = mk4(cvt_pk_bf16(qa1[0], qa1[1]), cvt_pk_bf16(qa1[2], qa1[3]));
  }

  f32x4 accO[2] = {f32x4{0.f, 0.f, 0.f, 0.f}, f32x4{0.f, 0.f, 0.f, 0.f}};
#pragma unroll 2
  for (int jt = 0; jt < 1024; jt += 16) {
    bf16x4 kf = {};
    if (lane < 32) kf = *(const bf16x4*)(&Kt[(size_t)(lg * 1024 + jt + li) * 4]);
    bf16x4 vf = {};
    if (li < 9) vf = *(const bf16x4*)(&Vt[li * VT_PITCH + jt + lg * 4]);
#pragma unroll
    for (int it2 = 0; it2 < 2; ++it2) {
      f32x4 st = mfma16(kf, qf[it2], f32x4{0.f, 0.f, 0.f, 0.f});  // S^T tile
      f32x4 p;
      p[0] = __ocml_native_exp2_f32(st[0]); p[1] = __ocml_native_exp2_f32(st[1]);
      p[2] = __ocml_native_exp2_f32(st[2]); p[3] = __ocml_native_exp2_f32(st[3]);
      bf16x4 pf = mk4(pk_trunc(p[0], p[1]), pk_trunc(p[2], p[3]));
      accO[it2] = mfma16(vf, pf, accO[it2]);                      // O^T += V''.P
    }
  }

  __syncthreads();                             // all jt done -> Kt LDS is dead
  float* OwW = (float*)Kt + w * 256;           // wave-private [tok 32][d 8]

#pragma unroll
  for (int it2 = 0; it2 < 2; ++it2) {
    float l = __shfl(accO[it2][0], 32 + li);   // denominator (ones row)
    float inv = 1.0f / l;
    if (lane < 32) {
      float4 o = make_float4(accO[it2][0] * inv, accO[it2][1] * inv,
                             accO[it2][2] * inv, accO[it2][3] * inv);
      *(float4*)(OwW + (it2 * 16 + li) * 8 + lg * 4) = o;   // same-wave RAW ok
    }
  }

  // out-projection: lane handles token tok, c-half ch (32 c's)
  const int tok = lane & 31, ch = lane >> 5;
  float ov[8];
#pragma unroll
  for (int d = 0; d < 8; ++d) ov[d] = OwW[tok * 8 + d];
#pragma unroll 4
  for (int j = 0; j < 32; ++j) {
    const int c = ch * 32 + j;
    float a = 0.f;
#pragma unroll
    for (int d = 0; d < 8; ++d) a += ov[d] * W0s[d * 64 + c];   // LDS broadcast
    atomicAdd(out + ((size_t)b * 64 + c) * T_DIM + i0w + tok, a);
  }
}

// ---------------------------------------------------------------------------
extern "C" void kernel_launch(void* const* d_in, const int* in_sizes, int n_in,
                              void* d_out, int out_size, void* d_ws, size_t ws_size,
                              hipStream_t stream) {
  const float* x    = (const float*)d_in[0];
  // d_in[1..4] = conv_w, conv_b, ln_g, ln_b : dead code in the reference
  const float* Wqkv = (const float*)d_in[5];
  const float* W0   = (const float*)d_in[6];
  const float* E    = (const float*)d_in[7];
  float* out = (float*)d_out;

  // workspace layout (~9 MB)
  float* partial     = (float*)d_ws;                   // 8 MB (8 s-slices)
  uint2* Kg          = (uint2*)(partial + 2097152);    // 0.5 MB
  unsigned short* Vg = (unsigned short*)(Kg + 65536);  // 0.5 MB

  k_front <<<dim3(256),      256, 0, stream>>>(x, E, partial, out);
  k_xkv   <<<dim3(16, 8, 4), 256, 0, stream>>>(partial, Wqkv, Kg, Vg);
  k_attn  <<<dim3(32, 32),   256, 0, stream>>>(x, Wqkv, Kg, Vg, W0, out);
}

// Round 6
// 157.656 us; speedup vs baseline: 1.0310x; 1.0310x over previous
//
#include <hip/hip_runtime.h>

// Dims fixed by setup_inputs(): B=4, C=64, H=W=64 -> T=4096, HEADS=8, dh=8, k=T/4=1024
#define T_DIM 4096
#define KD    1024
// K-scale with log2(e) folded in so attn uses native v_exp_f32 (2^x) directly
#define SCALE2 (0.35355339059327373f * 1.4426950408889634f)
#define VT_PITCH 1032

extern "C" __device__ float __ocml_native_exp2_f32(float);   // single v_exp_f32

typedef __attribute__((ext_vector_type(8))) short bf16x8;
typedef __attribute__((ext_vector_type(4))) float f32x4;
typedef __attribute__((ext_vector_type(16))) float f32x16;

__device__ inline unsigned short f2bf(float f) {   // RNE fp32 -> bf16
  unsigned u = __float_as_uint(f);
  unsigned r = u + 0x7fffu + ((u >> 16) & 1u);
  return (unsigned short)(r >> 16);
}

__device__ inline unsigned cvt_pk_bf16(float a, float b) {  // a->lo, b->hi (RNE)
  unsigned ua = __float_as_uint(a); ua += 0x7fffu + ((ua >> 16) & 1u);
  unsigned ub = __float_as_uint(b); ub += 0x7fffu + ((ub >> 16) & 1u);
  return (ua >> 16) | (ub & 0xffff0000u);
}

__device__ inline bf16x8 mk8(unsigned a, unsigned b, unsigned c, unsigned d) {
  union { unsigned u[4]; bf16x8 v; } x;
  x.u[0] = a; x.u[1] = b; x.u[2] = c; x.u[3] = d; return x.v;
}

// ---------------------------------------------------------------------------
// K1 "front": blocks 0..511  : xe — partial[s*4+b][c][k0..k0+63] (k-split:
//             kb 0..15, b 0..3, s 0..7; 512 blocks -> 2/CU, fixes R5's
//             1-block/CU latency stall). Each wave owns 16 k-cols.
//             blocks 512..1023: q — Q[bh][d][t] = x @ Wq (proven body).
//   ALSO: zeroes d_out (1 float4/thread) for k_attn's atomicAdd.
// ---------------------------------------------------------------------------
__global__ __launch_bounds__(256) void k_front(const float* __restrict__ x,
                                               const float* __restrict__ E,
                                               const float* __restrict__ Wqkv,
                                               float* __restrict__ partial,
                                               float* __restrict__ Q,
                                               float* __restrict__ out) {
  const int bid = blockIdx.x;
  const int tid = threadIdx.x;

  // zero d_out: 1024 blocks * 256 thr * 16 B = 4 MB, coalesced
  ((float4*)out)[(size_t)bid * 256 + tid] = make_float4(0.f, 0.f, 0.f, 0.f);

  if (bid < 512) {
    const int kb = bid & 15;                   // 0..15 -> 64 k-cols
    const int b  = (bid >> 4) & 3;             // 0..3
    const int s  = bid >> 6;                   // 0..7 (512 t-rows each)
    const int lane = tid & 63;
    const int w = tid >> 6;
    const int li = lane & 15, lg = lane >> 4;
    const int kcol = kb * 64 + w * 16 + li;

    f32x4 acc[4] = {};
#pragma unroll 2
    for (int tb = 0; tb < 16; ++tb) {
      const int tbase = s * 512 + tb * 32 + lg * 8;
      float bv[8];
#pragma unroll
      for (int j = 0; j < 8; ++j)
        bv[j] = E[(size_t)(tbase + j) * KD + kcol];
      bf16x8 bq = mk8(cvt_pk_bf16(bv[0], bv[1]), cvt_pk_bf16(bv[2], bv[3]),
                      cvt_pk_bf16(bv[4], bv[5]), cvt_pk_bf16(bv[6], bv[7]));
#pragma unroll
      for (int mt = 0; mt < 4; ++mt) {
        const float* ap = x + ((size_t)b * 64 + mt * 16 + li) * T_DIM + tbase;
        float4 a0 = *(const float4*)(ap);
        float4 a1 = *(const float4*)(ap + 4);
        bf16x8 af8 = mk8(cvt_pk_bf16(a0.x, a0.y), cvt_pk_bf16(a0.z, a0.w),
                         cvt_pk_bf16(a1.x, a1.y), cvt_pk_bf16(a1.z, a1.w));
        acc[mt] = __builtin_amdgcn_mfma_f32_16x16x32_bf16(af8, bq, acc[mt], 0, 0, 0);
      }
    }
    float* pb = partial + ((size_t)s * 4 + b) * (64 * KD);
#pragma unroll
    for (int mt = 0; mt < 4; ++mt) {
      const int row = mt * 16 + lg * 4;
#pragma unroll
      for (int reg = 0; reg < 4; ++reg)
        pb[(size_t)(row + reg) * KD + kcol] = acc[mt][reg];
    }
  } else {
    const int idx = bid - 512;
    const int g  = idx & 7;
    const int tt = (idx >> 3) & 15;
    const int b  = idx >> 7;
    const int t  = tt * 256 + tid;
    const int col0 = g * 24;

    float acc[8];
#pragma unroll
    for (int j = 0; j < 8; ++j) acc[j] = 0.f;
    const float* xb = x + (size_t)b * 64 * T_DIM + t;
#pragma unroll 4
    for (int c = 0; c < 64; ++c) {
      float xv = xb[(size_t)c * T_DIM];               // coalesced
      const float* wr = Wqkv + c * 192 + col0;        // wave-uniform -> s_load
#pragma unroll
      for (int h = 0; h < 8; ++h) acc[h] += xv * wr[h];
    }
#pragma unroll
    for (int h = 0; h < 8; ++h)
      Q[(((size_t)(b * 8 + h)) * 8 + g) * T_DIM + t] = acc[h];
  }
}

// ---------------------------------------------------------------------------
// K2 "xkv": s-reduce (8 slices, fp32 into LDS) + K/V projection, fused
//   (R4-proven). ONLY change: K is stored [j][8d] (kg[k*2+dg]) so k_attn can
//   read a full 16-B K-row per j for the 32x32 MFMA A-operand.
// ---------------------------------------------------------------------------
__global__ __launch_bounds__(256) void k_xkv(const float* __restrict__ partial,
                                             const float* __restrict__ Wqkv,
                                             uint2* __restrict__ Kg,
                                             unsigned short* __restrict__ Vg) {
  __shared__ float XPs[64 * 64];               // [c][k-local] fp32, 16 KB
  const int kb = blockIdx.x;                   // 0..15 -> k0 = kb*64
  const int h  = blockIdx.y;                   // 0..7
  const int b  = blockIdx.z;                   // 0..3
  const int tid = threadIdx.x;

  {
    const int kk = tid & 63;
    const int cg = tid >> 6;                   // 0..3
#pragma unroll 4
    for (int u = 0; u < 16; ++u) {
      const int c = cg * 16 + u;
      const size_t src = (size_t)c * KD + kb * 64 + kk;
      float a = 0.f;
#pragma unroll
      for (int s = 0; s < 8; ++s)
        a += partial[((size_t)s * 4 + b) * (64 * KD) + src];
      XPs[c * 64 + kk] = a;
    }
  }
  __syncthreads();

  const int klocal = tid & 63;
  const int sel    = (tid >> 6) & 1;           // wave-uniform: 0=K, 1=V
  const int dg     = tid >> 7;                 // wave-uniform: d-group 0/1
  const int k      = kb * 64 + klocal;

  float acc[4];
#pragma unroll
  for (int d = 0; d < 4; ++d) acc[d] = 0.f;
#pragma unroll 8
  for (int c = 0; c < 64; ++c) {
    float xv = XPs[c * 64 + klocal];                 // LDS, conflict-free
    const float* wr = Wqkv + c * 192 + (sel + 1) * 8 + h;            // s_load
#pragma unroll
    for (int d = 0; d < 4; ++d) acc[d] += xv * wr[(dg * 4 + d) * 24];
  }

  const int bh = b * 8 + h;
  if (sel == 0) {
    uint2* kg = Kg + (size_t)bh * 2048;
    // [j][8d] layout: d-halves of row k adjacent -> 16 B per j
    kg[k * 2 + dg] = make_uint2(cvt_pk_bf16(acc[0] * SCALE2, acc[1] * SCALE2),
                                cvt_pk_bf16(acc[2] * SCALE2, acc[3] * SCALE2));
  } else {
#pragma unroll
    for (int d = 0; d < 4; ++d)
      Vg[(size_t)(bh * 8 + dg * 4 + d) * KD + k] = f2bf(acc[d]);
  }
}

// ---------------------------------------------------------------------------
// K3: 32x32-MFMA flash attention + fused out-projection. Grid (bh 32, iy 32).
//   Per wave, per 32-j window:
//     S^T[32j][32i] = one mfma_f32_32x32x16_bf16 (A = K[j][8d] from LDS,
//                     half1 lanes zero; B = Q[d][i], half1 zero)
//     P = exp2(S^T) -> v_cvt_pk_bf16_f32 pairs -> two v_permlane32_swap_b32
//         per B-fragment gives the K=16 PV operand for BOTH lane halves
//     O^T += two fully-utilized 32x32x16 PV MFMAs (A = V''[d][j], ones row 8)
//   Denominator = ones-row (accO reg 4, half0) broadcast via one __shfl.
//   Epilogue (proven): normalized O -> wave-private LDS, project through W0
//   rows [h*8..h*8+8), atomicAdd into out (zeroed by k_front).
// ---------------------------------------------------------------------------
__global__ __launch_bounds__(256, 4) void k_attn(const float* __restrict__ Q,
                                              const uint2* __restrict__ Kg,
                                              const unsigned short* __restrict__ Vg,
                                              const float* __restrict__ W0,
                                              float* __restrict__ out) {
  __shared__ __attribute__((aligned(16))) unsigned short Kt[1024 * 8];  // [j][8d] 16 KB
  __shared__ unsigned short Vt[9 * VT_PITCH];   // [d][j] bf16, row 8 = ones
  __shared__ float W0s[512];                    // W0[h*8+d][c], d<8, c<64
  const int bh = blockIdx.x;
  const int tid = threadIdx.x;
  const int b = bh >> 3, h = bh & 7;

  const uint4* kg4 = (const uint4*)(Kg + (size_t)bh * 2048);
  uint4* kt4 = (uint4*)Kt;
#pragma unroll
  for (int it = 0; it < 4; ++it)
    kt4[it * 256 + tid] = kg4[it * 256 + tid];
  const unsigned* vg = (const unsigned*)(Vg + (size_t)bh * 8192);
#pragma unroll
  for (int dd = 0; dd < 8; ++dd) {
#pragma unroll
    for (int it = 0; it < 2; ++it) {
      const int j2 = it * 256 + tid;
      *(unsigned*)(Vt + dd * VT_PITCH + j2 * 2) = vg[dd * 512 + j2];
    }
  }
#pragma unroll
  for (int it = 0; it < 2; ++it)
    *(unsigned*)(Vt + 8 * VT_PITCH + (it * 256 + tid) * 2) = 0x3F803F80u;  // ones
  W0s[tid]       = W0[h * 512 + tid];          // rows h*8..h*8+7, coalesced
  W0s[tid + 256] = W0[h * 512 + tid + 256];
  __syncthreads();

  const int lane = tid & 63, w = tid >> 6;
  const int icol = lane & 31, half = lane >> 5;
  const int i0w = blockIdx.y * 128 + w * 32;

  // Q fragment: B[k=d][n=i], half0 lanes hold d 0..7 for col i, half1 zero
  bf16x8 qf8 = {};
  if (lane < 32) {
    const float* qp = Q + (size_t)bh * 8 * T_DIM + i0w + icol;
    float q0 = qp[0],          q1 = qp[T_DIM],     q2 = qp[2 * T_DIM];
    float q3 = qp[3 * T_DIM],  q4 = qp[4 * T_DIM], q5 = qp[5 * T_DIM];
    float q6 = qp[6 * T_DIM],  q7 = qp[7 * T_DIM];
    qf8 = mk8(cvt_pk_bf16(q0, q1), cvt_pk_bf16(q2, q3),
              cvt_pk_bf16(q4, q5), cvt_pk_bf16(q6, q7));
  }

  f32x16 accO = {};
  for (int jt = 0; jt < 1024; jt += 32) {
    // A of S-MFMA: K[j = jt + icol][d 0..7] (half1 lanes zero)
    bf16x8 kf8 = {};
    if (lane < 32) kf8 = *(const bf16x8*)(&Kt[(jt + lane) * 8]);
    f32x16 z = {};
    f32x16 st = __builtin_amdgcn_mfma_f32_32x32x16_bf16(kf8, qf8, z, 0, 0, 0);

    unsigned e0, e1, e2, e3, e4, e5, e6, e7;
    {
      float p0  = __ocml_native_exp2_f32(st[0]),  p1  = __ocml_native_exp2_f32(st[1]);
      float p2  = __ocml_native_exp2_f32(st[2]),  p3  = __ocml_native_exp2_f32(st[3]);
      float p4  = __ocml_native_exp2_f32(st[4]),  p5  = __ocml_native_exp2_f32(st[5]);
      float p6  = __ocml_native_exp2_f32(st[6]),  p7  = __ocml_native_exp2_f32(st[7]);
      float p8  = __ocml_native_exp2_f32(st[8]),  p9  = __ocml_native_exp2_f32(st[9]);
      float p10 = __ocml_native_exp2_f32(st[10]), p11 = __ocml_native_exp2_f32(st[11]);
      float p12 = __ocml_native_exp2_f32(st[12]), p13 = __ocml_native_exp2_f32(st[13]);
      float p14 = __ocml_native_exp2_f32(st[14]), p15 = __ocml_native_exp2_f32(st[15]);
      asm("v_cvt_pk_bf16_f32 %0, %1, %2" : "=v"(e0) : "v"(p0),  "v"(p1));
      asm("v_cvt_pk_bf16_f32 %0, %1, %2" : "=v"(e1) : "v"(p2),  "v"(p3));
      asm("v_cvt_pk_bf16_f32 %0, %1, %2" : "=v"(e2) : "v"(p4),  "v"(p5));
      asm("v_cvt_pk_bf16_f32 %0, %1, %2" : "=v"(e3) : "v"(p6),  "v"(p7));
      asm("v_cvt_pk_bf16_f32 %0, %1, %2" : "=v"(e4) : "v"(p8),  "v"(p9));
      asm("v_cvt_pk_bf16_f32 %0, %1, %2" : "=v"(e5) : "v"(p10), "v"(p11));
      asm("v_cvt_pk_bf16_f32 %0, %1, %2" : "=v"(e6) : "v"(p12), "v"(p13));
      asm("v_cvt_pk_bf16_f32 %0, %1, %2" : "=v"(e7) : "v"(p14), "v"(p15));
    }
    // cross-half exchange: after these, (e0,e1,e2,e3) and (e4,e5,e6,e7) are
    // the K=16 B-fragments (P[j][i]) for PV1 (j jt..jt+15) / PV2 (jt+16..31)
    asm("v_permlane32_swap_b32 %0, %1" : "+v"(e0), "+v"(e2));
    asm("v_permlane32_swap_b32 %0, %1" : "+v"(e1), "+v"(e3));
    asm("v_permlane32_swap_b32 %0, %1" : "+v"(e4), "+v"(e6));
    asm("v_permlane32_swap_b32 %0, %1" : "+v"(e5), "+v"(e7));

    // A of PV: V''[d = icol][j], rows 9..31 zero, row 8 = ones (denominator)
    bf16x8 va0 = {}, va1 = {};
    if (icol < 9) {
      const unsigned short* vp = Vt + icol * VT_PITCH + jt + half * 8;
      va0 = *(const bf16x8*)(vp);
      va1 = *(const bf16x8*)(vp + 16);
    }
    accO = __builtin_amdgcn_mfma_f32_32x32x16_bf16(va0, mk8(e0, e1, e2, e3), accO, 0, 0, 0);
    accO = __builtin_amdgcn_mfma_f32_32x32x16_bf16(va1, mk8(e4, e5, e6, e7), accO, 0, 0, 0);
  }

  __syncthreads();                             // all jt done -> Kt LDS is dead
  float* OwW = (float*)Kt + w * 256;           // wave-private [tok 32][d 8]

  {
    float inv = 1.0f / __shfl(accO[4], icol);  // ones-row (row 8, half0 reg 4)
    float4 o = make_float4(accO[0] * inv, accO[1] * inv,
                           accO[2] * inv, accO[3] * inv);   // d = half*4 + r
    *(float4*)(OwW + icol * 8 + half * 4) = o;   // same-wave RAW ok
  }

  // out-projection: lane handles token tok, c-half ch (32 c's)
  const int tok = icol, ch = half;
  float ov[8];
#pragma unroll
  for (int d = 0; d < 8; ++d) ov[d] = OwW[tok * 8 + d];
#pragma unroll 4
  for (int j = 0; j < 32; ++j) {
    const int c = ch * 32 + j;
    float a = 0.f;
#pragma unroll
    for (int d = 0; d < 8; ++d) a += ov[d] * W0s[d * 64 + c];   // LDS broadcast
    atomicAdd(out + ((size_t)b * 64 + c) * T_DIM + i0w + tok, a);
  }
}

// ---------------------------------------------------------------------------
extern "C" void kernel_launch(void* const* d_in, const int* in_sizes, int n_in,
                              void* d_out, int out_size, void* d_ws, size_t ws_size,
                              hipStream_t stream) {
  const float* x    = (const float*)d_in[0];
  // d_in[1..4] = conv_w, conv_b, ln_g, ln_b : dead code in the reference
  const float* Wqkv = (const float*)d_in[5];
  const float* W0   = (const float*)d_in[6];
  const float* E    = (const float*)d_in[7];
  float* out = (float*)d_out;

  // workspace layout (~13 MB)
  float* Q           = (float*)d_ws;                   // 4 MB
  float* partial     = Q + 1048576;                    // 8 MB (8 s-slices)
  uint2* Kg          = (uint2*)(partial + 2097152);    // 0.5 MB
  unsigned short* Vg = (unsigned short*)(Kg + 65536);  // 0.5 MB

  k_front <<<dim3(1024),     256, 0, stream>>>(x, E, Wqkv, partial, Q, out);
  k_xkv   <<<dim3(16, 8, 4), 256, 0, stream>>>(partial, Wqkv, Kg, Vg);
  k_attn  <<<dim3(32, 32),   256, 0, stream>>>(Q, Kg, Vg, W0, out);
}